// Round 2
// baseline (225.547 us; speedup 1.0000x reference)
//
#include <hip/hip_runtime.h>
#include <math.h>

// mat2twist: in = B x 3x3 fp32 rotation matrices (row-major), out = B x 3 axis-angle.
// Memory-bound: 151 MB in + 50 MB out => roofline ~32 us at 6.3 TB/s.
//
// Round-1 lesson: per-thread float4 loads at 144B lane stride thrash L1/L2
// (~9x over-fetch, measured 223 us). Fix: stage through LDS so every global
// access is linearly coalesced (lane i -> base + 16*i).
//
// Block = 256 threads, owns 256 quads (1024 matrices):
//   load  256*9  float4 (36 KB) coalesced -> LDS
//   each thread computes 4 matrices from its 36 LDS floats (144B stride = 2-way
//   bank aliasing, free on CDNA4)
//   barrier, reuse LDS, write 256*3 float4 (12 KB) coalesced -> global.

__global__ __launch_bounds__(256) void mat2twist_lds_kernel(
    const float4* __restrict__ in4,   // n_quads * 9 float4
    float4* __restrict__ out4,        // n_quads * 3 float4
    int n_quads,
    const float* __restrict__ in_s,   // scalar views for tail (n_mat % 4)
    float* __restrict__ out_s,
    int n_mat) {

    __shared__ float4 lds[256 * 9];   // 36 KB, reused for output

    const int t = threadIdx.x;

    for (int qbase = blockIdx.x * 256; qbase < n_quads; qbase += gridDim.x * 256) {
        const int quads_here = min(256, n_quads - qbase);
        const int in_total4  = quads_here * 9;

        // ---- coalesced global -> LDS ----
        const float4* src = in4 + (size_t)qbase * 9;
        for (int i = t; i < in_total4; i += 256) {
            lds[i] = src[i];
        }
        __syncthreads();

        // ---- compute: thread t owns quad (qbase + t) = 4 matrices ----
        float r[12];
        const bool active = t < quads_here;
        if (active) {
            const float* m = (const float*)(lds + t * 9);  // 36 floats, 16B aligned
#pragma unroll
            for (int j = 0; j < 4; ++j) {
                const float* a = m + 9 * j;   // row-major 3x3
                float tr  = a[0] + a[4] + a[8];
                float c   = 0.5f * (tr - 1.0f);
                float ang = acosf(c);
                // sin(acos(c)) = sqrt(1-c^2); theta in [0.1, pi-0.1] -> safe
                float s2  = fmaxf(1.0f - c * c, 1e-30f);
                float k   = ang * 0.5f / sqrtf(s2);
                r[3 * j + 0] = k * (a[7] - a[5]);
                r[3 * j + 1] = k * (a[2] - a[6]);
                r[3 * j + 2] = k * (a[3] - a[1]);
            }
        }
        __syncthreads();   // all LDS reads done before overwrite

        if (active) {
            lds[t * 3 + 0] = make_float4(r[0], r[1], r[2],  r[3]);
            lds[t * 3 + 1] = make_float4(r[4], r[5], r[6],  r[7]);
            lds[t * 3 + 2] = make_float4(r[8], r[9], r[10], r[11]);
        }
        __syncthreads();

        // ---- coalesced LDS -> global ----
        float4* dst = out4 + (size_t)qbase * 3;
        const int out_total4 = quads_here * 3;
        for (int i = t; i < out_total4; i += 256) {
            dst[i] = lds[i];
        }
        __syncthreads();   // protect LDS before next grid-stride iteration
    }

    // ---- scalar tail (n_mat % 4) — empty for B = 4194304 ----
    if (blockIdx.x == 0 && t == 0) {
        for (int i = n_quads * 4; i < n_mat; ++i) {
            const float* a = in_s + (size_t)i * 9;
            float tr  = a[0] + a[4] + a[8];
            float c   = 0.5f * (tr - 1.0f);
            float ang = acosf(c);
            float s2  = fmaxf(1.0f - c * c, 1e-30f);
            float k   = ang * 0.5f / sqrtf(s2);
            out_s[3 * i + 0] = k * (a[7] - a[5]);
            out_s[3 * i + 1] = k * (a[2] - a[6]);
            out_s[3 * i + 2] = k * (a[3] - a[1]);
        }
    }
}

extern "C" void kernel_launch(void* const* d_in, const int* in_sizes, int n_in,
                              void* d_out, int out_size, void* d_ws, size_t ws_size,
                              hipStream_t stream) {
    const float* in = (const float*)d_in[0];
    float* out = (float*)d_out;
    const int n_mat   = in_sizes[0] / 9;
    const int n_quads = n_mat / 4;

    int grid = (n_quads + 255) / 256;       // 4096 for B = 4194304
    if (grid > 8192) grid = 8192;           // grid-stride beyond this
    if (grid < 1) grid = 1;

    mat2twist_lds_kernel<<<grid, 256, 0, stream>>>(
        (const float4*)in, (float4*)out, n_quads, in, out, n_mat);
}

// Round 3
// 221.902 us; speedup vs baseline: 1.0164x; 1.0164x over previous
//
#include <hip/hip_runtime.h>
#include <math.h>

// mat2twist: in = B x 3x3 fp32 rotation matrices (row-major), out = B x 3 axis-angle.
// Pure streaming, 201 MB total traffic, HBM floor ~32 us.
//
// Main kernel: branch-free, full tiles only. Block = 256 threads = 256 quads
// (1024 matrices). 9 unrolled float4 loads (lane-linear, coalesced) -> LDS;
// one barrier; each thread computes 4 matrices from its 36 LDS floats
// (144 B LDS stride = 2-way bank aliasing, free on CDNA4); 3 direct float4
// stores (48 B lane stride; wave's 3 KB span fully covered -> L2 merges).
// Tail kernel handles n_mat % 1024 (empty for B = 4194304).

__device__ __forceinline__ void twist1(const float* __restrict__ a,
                                       float* __restrict__ r) {
    float tr  = a[0] + a[4] + a[8];
    float c   = 0.5f * (tr - 1.0f);
    float ang = acosf(c);
    // sin(acos(c)) = sqrt(1-c^2); theta in [0.1, pi-0.1] -> s2 bounded away from 0
    float s2  = fmaxf(1.0f - c * c, 1e-30f);
    float k   = ang * 0.5f * rsqrtf(s2);
    r[0] = k * (a[7] - a[5]);
    r[1] = k * (a[2] - a[6]);
    r[2] = k * (a[3] - a[1]);
}

__global__ __launch_bounds__(256) void mat2twist_main(
    const float4* __restrict__ in4,   // full tiles: gridDim.x * 256 quads
    float4* __restrict__ out4) {

    __shared__ float4 lds[256 * 9];   // 36 KB -> 4 blocks/CU
    const int t = threadIdx.x;
    const size_t qb = (size_t)blockIdx.x * 256;

    // ---- coalesced global -> LDS (9 loads in flight, then 9 ds_writes) ----
    const float4* __restrict__ src = in4 + qb * 9;
    float4 v[9];
#pragma unroll
    for (int j = 0; j < 9; ++j) v[j] = src[t + 256 * j];
#pragma unroll
    for (int j = 0; j < 9; ++j) lds[t + 256 * j] = v[j];
    __syncthreads();

    // ---- compute 4 matrices ----
    const float* m = (const float*)(lds + (size_t)t * 9);
    float r[12];
#pragma unroll
    for (int j = 0; j < 4; ++j) twist1(m + 9 * j, r + 3 * j);

    // ---- direct stores, 3 x float4 per thread ----
    float4* __restrict__ dst = out4 + qb * 3 + (size_t)t * 3;
    dst[0] = make_float4(r[0], r[1], r[2],  r[3]);
    dst[1] = make_float4(r[4], r[5], r[6],  r[7]);
    dst[2] = make_float4(r[8], r[9], r[10], r[11]);
}

__global__ __launch_bounds__(256) void mat2twist_tail(
    const float* __restrict__ in, float* __restrict__ out,
    int start, int n_mat) {
    int i = start + blockIdx.x * blockDim.x + threadIdx.x;
    if (i < n_mat) {
        float a[9];
#pragma unroll
        for (int j = 0; j < 9; ++j) a[j] = in[(size_t)i * 9 + j];
        float r[3];
        twist1(a, r);
        out[(size_t)i * 3 + 0] = r[0];
        out[(size_t)i * 3 + 1] = r[1];
        out[(size_t)i * 3 + 2] = r[2];
    }
}

extern "C" void kernel_launch(void* const* d_in, const int* in_sizes, int n_in,
                              void* d_out, int out_size, void* d_ws, size_t ws_size,
                              hipStream_t stream) {
    const float* in = (const float*)d_in[0];
    float* out = (float*)d_out;
    const int n_mat = in_sizes[0] / 9;

    const int full_blocks = n_mat / 1024;           // 4096 for B = 4194304
    if (full_blocks > 0) {
        mat2twist_main<<<full_blocks, 256, 0, stream>>>(
            (const float4*)in, (float4*)out);
    }
    const int start = full_blocks * 1024;
    const int rem = n_mat - start;
    if (rem > 0) {
        mat2twist_tail<<<(rem + 255) / 256, 256, 0, stream>>>(
            in, out, start, n_mat);
    }
}